// Round 2
// baseline (392.547 us; speedup 1.0000x reference)
//
#include <hip/hip_runtime.h>
#include <cfloat>
#include <cstddef>

// VQ-VAE vector quantizer, MI355X / gfx950.
// z: (32, 64, 32, 32) f32 BCHW; embedding: (1024, 64) f32.
// Outputs concatenated f32: loss[1], z_q(BCHW)[2097152], perplexity[1],
// min_encodings[32768*1024], min_encoding_indices(as float)[32768].
//
// Argmin: emulate the reference's fp32 rounding (NOT exact math):
//   d_j = fl32( fl32(z2 + e2_j) - 2*dot_j )  at magnitude ~64,
// with z2/e2 double-accumulated and rounded once to fp32, dot via fp32 fma
// chains (error << ulp(64)); first-index tie-break matches np.argmin.
// Scan is ascending-index, so "first min" == strict <.
// Packed-fp32 note: v_pk_fma_f32 performs two independent fp32 FMAs with
// identical per-element rounding; the chains (a0,a1)/(a2,a3) and the final
// (a0+a1)+(a2+a3) reduction order are unchanged -> bit-identical to the
// version that passed with absmax 0.0.
//
// R2 change: codebook scan loads were readfirstlane-forced SCALAR loads.
// 16 waves/CU stream 512 KB of disjoint chunks through the 16 KB sL1 ->
// ~100% miss, and 512 B/iter needs 128 SGPRs so the compiler cannot
// double-buffer in the 112-SGPR budget -> every iteration exposes L2
// latency -> VALUBusy 37%. Now: per-lane (uniform-value) vector loads ->
// global_load_dwordx4 broadcast, 63-deep vmcnt queue + VGPR-buffered
// software pipelining hides L2 latency. Plus float2/v_pk_fma packing
// halves scan VALU issue.

#define NROWS      32768          // B*H*W
#define NE         1024
#define EDIM       64
#define RPB        64             // rows per block
#define NBLK       (NROWS / RPB)  // 512
#define TPB        512            // 8 waves: each scans 128 codes

#define OFF_LOSS   ((size_t)0)
#define OFF_ZQ     ((size_t)1)
#define OFF_PERP   ((size_t)2097153)
#define OFF_OH     ((size_t)2097154)
#define OFF_IDX    ((size_t)35651586)

typedef float v2f __attribute__((ext_vector_type(2)));

// ws layout (bytes): [0,4096) int hist[1024]; [4096,6144) float partial[512]

__global__ __launch_bounds__(TPB, 4) void vq_main(const float* __restrict__ z,
                                                  const float* __restrict__ emb,
                                                  int* __restrict__ hist,
                                                  float* __restrict__ partial,
                                                  float* __restrict__ out) {
    const int t    = threadIdx.x;
    const int lane = t & 63;
    const int q    = t >> 6;          // wave id, 0..7
    const int r0   = blockIdx.x * RPB;
    const int row  = r0 + lane;       // this lane's z-row
    const int b    = row >> 10;       // batch (1024 rows per batch image)
    const int m    = row & 1023;      // h*32+w
    const size_t zbase = (size_t)b * 65536 + (size_t)m;

    __shared__ float s_e2[NE];
    __shared__ float s_d[8][64];
    __shared__ int   s_j[8][64];
    __shared__ int   s_idx[64];
    __shared__ float s_l[8];

    // ---- per-block ||e_j||^2 into LDS (double-accumulated, fp32-rounded) --
    for (int j = t; j < NE; j += TPB) {
        const float4* e4 = (const float4*)(emb + ((size_t)j << 6));
        double s = 0.0;
#pragma unroll
        for (int k = 0; k < 16; ++k) {
            float4 v = e4[k];
            s += (double)v.x * (double)v.x;
            s += (double)v.y * (double)v.y;
            s += (double)v.z * (double)v.z;
            s += (double)v.w * (double)v.w;
        }
        s_e2[j] = (float)s;
    }

    // ---- load this lane's z row (64 ch, stride 1024 floats) into VGPRs ----
    float4 zr[16];
#pragma unroll
    for (int k = 0; k < 16; ++k) {
        float4 v;
        v.x = z[zbase + (size_t)(4 * k + 0) * 1024];
        v.y = z[zbase + (size_t)(4 * k + 1) * 1024];
        v.z = z[zbase + (size_t)(4 * k + 2) * 1024];
        v.w = z[zbase + (size_t)(4 * k + 3) * 1024];
        zr[k] = v;
    }

    // ---- ||z||^2 in double, rounded once to fp32 ----
    double z2d = 0.0;
#pragma unroll
    for (int k = 0; k < 16; ++k) {
        z2d += (double)zr[k].x * (double)zr[k].x;
        z2d += (double)zr[k].y * (double)zr[k].y;
        z2d += (double)zr[k].z * (double)zr[k].z;
        z2d += (double)zr[k].w * (double)zr[k].w;
    }
    const float z2f = (float)z2d;

    __syncthreads();   // s_e2 ready

    // ---- fire-and-forget zero-fill of this block's one-hot slab ----------
    // Slab: 64 rows x 1024 cols = 65536 floats, contiguous at OFF_OH+r0*1024.
    // Byte address is ==8 (mod 16): head/tail float2, middle 16383 float4.
    // Stores drain to L2/HBM under the VALU scan; the combine barrier's
    // implicit vmcnt(0) orders the 1.0f scatter after them.
    {
        float* ohb = out + OFF_OH + (size_t)r0 * 1024;
        if (t == 0) {
            *(float2*)ohb             = make_float2(0.f, 0.f);
            *(float2*)(ohb + 65534)   = make_float2(0.f, 0.f);
        }
        float4* p4 = (float4*)(ohb + 2);          // 16B-aligned
        const float4 z4 = make_float4(0.f, 0.f, 0.f, 0.f);
        for (int i = t; i < 16383; i += TPB) p4[i] = z4;
    }

    // ---- scan this wave's 128-code chunk, 2 codes per iteration ----
    // jbase is wave-uniform in VALUE but divergence analysis sees it as
    // divergent (derived from threadIdx) -> VECTOR loads: uniform-address
    // global_load_dwordx4 coalesces to a single broadcast L2 request and
    // pipelines deeply through the vmcnt queue (the scalar path could not
    // buffer even one iteration in the SGPR budget).
    const int jbase = q << 7;
    float bestd = FLT_MAX;
    int   bestj = NE;
    for (int jj = 0; jj < 128; jj += 2) {
        const int ja = jbase + jj;
        const int jb = ja + 1;
        const float4* ea = (const float4*)(emb + ((size_t)ja << 6));
        const float4* eb = (const float4*)(emb + ((size_t)jb << 6));
        v2f a01 = {0.f, 0.f}, a23 = {0.f, 0.f};
        v2f b01 = {0.f, 0.f}, b23 = {0.f, 0.f};
#pragma unroll
        for (int k = 0; k < 16; ++k) {
            float4 av = ea[k];
            float4 bv = eb[k];
            v2f axy = {av.x, av.y}, azw = {av.z, av.w};
            v2f bxy = {bv.x, bv.y}, bzw = {bv.z, bv.w};
            v2f zxy = {zr[k].x, zr[k].y}, zzw = {zr[k].z, zr[k].w};
            a01 = __builtin_elementwise_fma(axy, zxy, a01);  // v_pk_fma_f32
            a23 = __builtin_elementwise_fma(azw, zzw, a23);
            b01 = __builtin_elementwise_fma(bxy, zxy, b01);
            b23 = __builtin_elementwise_fma(bzw, zzw, b23);
        }
        float dota = (a01.x + a01.y) + (a23.x + a23.y);
        float dotb = (b01.x + b01.y) + (b23.x + b23.y);
        // reference fp32 rounding sequence (two roundings at magnitude ~64)
        float da = (z2f + s_e2[ja]) - 2.0f * dota;
        float db = (z2f + s_e2[jb]) - 2.0f * dotb;
        // ascending scan: strict < keeps the first (lowest-index) minimum
        if (da < bestd) { bestd = da; bestj = ja; }
        if (db < bestd) { bestd = db; bestj = jb; }
    }

    // ---- combine 8 per-wave candidates per row; first-index tie-break ----
    s_d[q][lane] = bestd;
    s_j[q][lane] = bestj;
    __syncthreads();   // implicit vmcnt(0): zero-fill now globally visible
    if (t < 64) {
        float bd = s_d[0][t];
        int   bj = s_j[0][t];
#pragma unroll
        for (int w = 1; w < 8; ++w) {   // ascending w = ascending code chunks
            float dw = s_d[w][t];
            if (dw < bd) { bd = dw; bj = s_j[w][t]; }
        }
        s_idx[t] = bj;
        out[OFF_IDX + (size_t)(r0 + t)] = (float)bj;   // indices as float
        // one-hot: single 1.0f per row on top of the zero slab
        out[OFF_OH + (size_t)(r0 + t) * 1024 + bj] = 1.0f;
        atomicAdd(&hist[bj], 1);
    }
    __syncthreads();

    // ---- z_q (straight-through) + loss partial ----
    // wave q handles channels c = q, q+8, ... for its lane's row
    const int    jjx = s_idx[lane];
    const float* er  = emb + ((size_t)jjx << 6);
    float* zq = out + OFF_ZQ + (size_t)b * 65536 + (size_t)m;
    float lsum = 0.f;
#pragma unroll
    for (int c = q; c < EDIM; c += 8) {
        float zc   = z[zbase + (size_t)c * 1024];   // coalesced across lanes
        float ev   = er[c];                         // gather (L2-hot)
        float diff = ev - zc;
        zq[(size_t)c * 1024] = zc + diff;           // mimic zp + (z_q - zp)
        lsum = fmaf(diff, diff, lsum);
    }
#pragma unroll
    for (int off = 32; off >= 1; off >>= 1) lsum += __shfl_down(lsum, off);
    if (lane == 0) s_l[q] = lsum;
    __syncthreads();
    if (t == 0) {
        float l = 0.f;
#pragma unroll
        for (int w = 0; w < 8; ++w) l += s_l[w];
        partial[blockIdx.x] = l;
    }
}

__global__ __launch_bounds__(1024) void vq_final(const int* __restrict__ hist,
                                                 const float* __restrict__ partial,
                                                 float* __restrict__ out) {
    int t = threadIdx.x;
    float p    = (float)hist[t] * (1.0f / 32768.0f);
    float term = p * logf(p + 1e-10f);
    float lp   = (t < NBLK) ? partial[t] : 0.f;
#pragma unroll
    for (int off = 32; off >= 1; off >>= 1) {
        term += __shfl_down(term, off);
        lp   += __shfl_down(lp, off);
    }
    __shared__ float st[16], sl[16];
    int w = t >> 6, ln = t & 63;
    if (ln == 0) { st[w] = term; sl[w] = lp; }
    __syncthreads();
    if (t == 0) {
        float s = 0.f, l = 0.f;
#pragma unroll
        for (int i = 0; i < 16; ++i) { s += st[i]; l += sl[i]; }
        out[OFF_LOSS] = 1.25f * l * (1.0f / 2097152.0f);  // (1+beta)*mean
        out[OFF_PERP] = expf(-s);
    }
}

extern "C" void kernel_launch(void* const* d_in, const int* in_sizes, int n_in,
                              void* d_out, int out_size, void* d_ws, size_t ws_size,
                              hipStream_t stream) {
    const float* z   = (const float*)d_in[0];
    const float* emb = (const float*)d_in[1];
    float* out     = (float*)d_out;
    int*   hist    = (int*)d_ws;
    float* partial = (float*)((char*)d_ws + 4096);

    hipMemsetAsync(hist, 0, 4096, stream);
    vq_main<<<NBLK, TPB, 0, stream>>>(z, emb, hist, partial, out);
    vq_final<<<1, 1024, 0, stream>>>(hist, partial, out);
}

// Round 3
// 264.875 us; speedup vs baseline: 1.4820x; 1.4820x over previous
//
#include <hip/hip_runtime.h>
#include <cfloat>
#include <cstddef>

// VQ-VAE vector quantizer, MI355X / gfx950.
// z: (32, 64, 32, 32) f32 BCHW; embedding: (1024, 64) f32.
// Outputs concatenated f32: loss[1], z_q(BCHW)[2097152], perplexity[1],
// min_encodings[32768*1024], min_encoding_indices(as float)[32768].
//
// R3 layout transpose. History:
//   R1 (108us): lanes own rows, codebook via wave-uniform SCALAR loads ->
//     s_load latency exposed (112-SGPR budget can't double-buffer 512B/iter),
//     VALUBusy 37%.
//   R2 (284us): per-lane VECTOR loads of uniform addresses -> 64x redundant
//     vL1/RF traffic, VALUBusy 15%. Theory refuted: uniform-address vector
//     loads are NOT a free broadcast.
//   R3: lane t owns code j==t in 64 VGPRs (loaded ONCE, 16x dwordx4);
//     block stages its 128 z-rows in LDS; scan loops rows with same-address
//     ds_read broadcast (conflict-free, lgkm-only -> zero-fill stores drain
//     underneath). Argmin per row: 6-stage shfl_xor fminf butterfly + ballot;
//     winning index = jbase + ffs(ballot) (j affine in lane, lowest lane ==
//     lowest index == np.argmin first-index tie-break).
//
// Numerics (bit-exact vs reference, absmax 0.0 in R1/R2):
//   dot: 4 fp32 fma chains over k ascending (x,y,z,w), final (a0+a1)+(a2+a3)
//        via v_pk_fma_f32 pairs (R2 proved pk path bit-exact).
//   e2/z2: sequential double accumulation (ch ascending), rounded once.
//   d = (z2f + e2f) - 2.0f*dot  (two fp32 roundings at magnitude ~64).
//   loss: reduction tree kept IDENTICAL to R1 — each 128-row block emits two
//   64-row partials with R1's exact wave/lane/shfl_down structure, so
//   partial[512] and vq_final are bit-for-bit unchanged.

#define NROWS      32768          // B*H*W
#define NE         1024
#define EDIM       64
#define RPB        128            // rows per block
#define NBLK       (NROWS / RPB)  // 256 blocks = 1 per CU
#define TPB        1024           // 16 waves; lane t owns code j = t
#define NPART      512            // loss partials (2 per block, R1-compatible)

#define OFF_LOSS   ((size_t)0)
#define OFF_ZQ     ((size_t)1)
#define OFF_PERP   ((size_t)2097153)
#define OFF_OH     ((size_t)2097154)
#define OFF_IDX    ((size_t)35651586)

typedef float v2f __attribute__((ext_vector_type(2)));

// ws layout (bytes): [0,4096) int hist[1024]; [4096,6144) float partial[512]

__global__ __launch_bounds__(TPB) void vq_main(const float* __restrict__ z,
                                               const float* __restrict__ emb,
                                               int* __restrict__ hist,
                                               float* __restrict__ partial,
                                               float* __restrict__ out) {
    const int t    = threadIdx.x;
    const int lane = t & 63;
    const int q    = t >> 6;          // wave id, 0..15
    const int r0   = blockIdx.x * RPB;
    const int b    = r0 >> 10;        // 128 | 1024 -> batch const per block
    const int m0   = r0 & 1023;
    const size_t zb0 = (size_t)b * 65536 + (size_t)m0;

    __shared__ float s_z[RPB][68];    // z-rows, stride 68 (16B-aligned rows)
    __shared__ float s_z2[RPB];
    __shared__ float s_d[16][RPB];
    __shared__ int   s_j[16][RPB];
    __shared__ int   s_idx[RPB];
    __shared__ float s_l[16];

    // ---- codebook: lane t owns code j = t; 64 floats -> 16 float4 regs ----
    float4 cb[16];
    {
        const float4* ep = (const float4*)(emb + ((size_t)t << 6));
#pragma unroll
        for (int k = 0; k < 16; ++k) cb[k] = ep[k];
    }
    // ||e_j||^2: sequential double accumulation, ch ascending, one rounding
    float e2f;
    {
        double s = 0.0;
#pragma unroll
        for (int k = 0; k < 16; ++k) {
            s += (double)cb[k].x * (double)cb[k].x;
            s += (double)cb[k].y * (double)cb[k].y;
            s += (double)cb[k].z * (double)cb[k].z;
            s += (double)cb[k].w * (double)cb[k].w;
        }
        e2f = (float)s;
    }

    // ---- stage 128 z-rows into LDS (transpose BCHW -> [row][ch]) ----------
    // item i (0..2047): c = i>>5, f4 = i&31 -> float4 of rows 4f4..4f4+3.
    // Global reads: 32 consecutive threads cover 512B contiguous -> coalesced.
#pragma unroll
    for (int it = 0; it < 2; ++it) {
        int i  = t + it * TPB;
        int c  = i >> 5;
        int f4 = i & 31;
        float4 v = *(const float4*)(z + zb0 + (size_t)c * 1024 + 4 * f4);
        s_z[4 * f4 + 0][c] = v.x;
        s_z[4 * f4 + 1][c] = v.y;
        s_z[4 * f4 + 2][c] = v.z;
        s_z[4 * f4 + 3][c] = v.w;
    }
    __syncthreads();   // s_z ready (no stores outstanding yet -> cheap drain)

    // ---- fire-and-forget zero-fill of this block's one-hot slab ----------
    // 128 rows x 1024 = 512 KB contiguous; base byte addr == 8 (mod 16).
    // No vmcnt wait exists between here and the post-scan __syncthreads():
    // the scan is ds_read/VALU only, and the mid barrier below waits lgkm
    // only -> these stores drain under ~20+ us of compute.
    {
        float* ohb = out + OFF_OH + (size_t)r0 * 1024;
        if (t == 0) {
            *(float2*)ohb              = make_float2(0.f, 0.f);
            *(float2*)(ohb + 131070)   = make_float2(0.f, 0.f);
        }
        float4* p4 = (float4*)(ohb + 2);          // 16B-aligned
        const float4 z4 = make_float4(0.f, 0.f, 0.f, 0.f);
        for (int i = t; i < 32767; i += TPB) p4[i] = z4;
    }

    // ---- ||z_r||^2 per row (double, ch ascending, one rounding) ----------
    if (t < RPB) {
        const float4* zr = (const float4*)&s_z[t][0];
        double s = 0.0;
#pragma unroll
        for (int k = 0; k < 16; ++k) {
            float4 v = zr[k];
            s += (double)v.x * (double)v.x;
            s += (double)v.y * (double)v.y;
            s += (double)v.z * (double)v.z;
            s += (double)v.w * (double)v.w;
        }
        s_z2[t] = (float)s;
    }
    // raw barrier: LDS producers flushed (lgkmcnt 0), but NO vmcnt drain --
    // the zero-fill stores above stay in flight through the scan.
    asm volatile("s_waitcnt lgkmcnt(0)" ::: "memory");
    __builtin_amdgcn_s_barrier();

    // ---- scan: rows broadcast from LDS, 2 rows per iteration --------------
    const int jbase = q << 6;         // this wave covers codes [jbase, jbase+64)
    float kdA = 0.f, kdB = 0.f;       // kept (d,j) for local rows lane / lane+64
    int   kjA = 0,   kjB = 0;         // (always overwritten exactly once each)
    for (int rb = 0; rb < RPB; rb += 2) {
        const float4* zr0 = (const float4*)&s_z[rb][0];
        const float4* zr1 = (const float4*)&s_z[rb + 1][0];
        v2f a01 = {0.f, 0.f}, a23 = {0.f, 0.f};
        v2f b01 = {0.f, 0.f}, b23 = {0.f, 0.f};
#pragma unroll
        for (int k = 0; k < 16; ++k) {
            float4 e  = cb[k];
            float4 z0 = zr0[k];       // ds_read_b128, same addr all lanes
            float4 z1 = zr1[k];
            v2f exy = {e.x, e.y},  ezw = {e.z, e.w};
            v2f x0  = {z0.x, z0.y}, w0 = {z0.z, z0.w};
            v2f x1  = {z1.x, z1.y}, w1 = {z1.z, z1.w};
            a01 = __builtin_elementwise_fma(x0, exy, a01);  // v_pk_fma_f32
            a23 = __builtin_elementwise_fma(w0, ezw, a23);
            b01 = __builtin_elementwise_fma(x1, exy, b01);
            b23 = __builtin_elementwise_fma(w1, ezw, b23);
        }
        float dota = (a01.x + a01.y) + (a23.x + a23.y);
        float dotb = (b01.x + b01.y) + (b23.x + b23.y);
        float da = (s_z2[rb]     + e2f) - 2.0f * dota;
        float db = (s_z2[rb + 1] + e2f) - 2.0f * dotb;
        // wave-wide min (value only), two rows interleaved for ILP
        float ma = da, mb = db;
#pragma unroll
        for (int off = 1; off < 64; off <<= 1) {
            ma = fminf(ma, __shfl_xor(ma, off));
            mb = fminf(mb, __shfl_xor(mb, off));
        }
        // first-index winner: lowest lane with d == min  (j = jbase + lane)
        unsigned long long ba = __ballot(da == ma);
        unsigned long long bb = __ballot(db == mb);
        int ja = jbase + (__ffsll((long long)ba) - 1);
        int jb = jbase + (__ffsll((long long)bb) - 1);
        // local row rb   -> kept by lane rb&63 ; row rb+1 -> lane (rb+1)&63
        if (rb < 64) {
            if (lane == (rb & 63))       { kdA = ma; kjA = ja; }
            if (lane == ((rb + 1) & 63)) { kdA = mb; kjA = jb; }
        } else {
            if (lane == (rb & 63))       { kdB = ma; kjB = ja; }
            if (lane == ((rb + 1) & 63)) { kdB = mb; kjB = jb; }
        }
    }
    s_d[q][lane]      = kdA;  s_j[q][lane]      = kjA;
    s_d[q][lane + 64] = kdB;  s_j[q][lane + 64] = kjB;
    __syncthreads();   // full barrier: vmcnt(0) -> zero-fill globally visible

    // ---- combine 16 per-wave candidates per row (ascending code chunks) ---
    if (t < RPB) {
        float bd = s_d[0][t];
        int   bj = s_j[0][t];
#pragma unroll
        for (int w = 1; w < 16; ++w) {
            float dw = s_d[w][t];
            if (dw < bd) { bd = dw; bj = s_j[w][t]; }  // strict <: first index
        }
        s_idx[t] = bj;
        out[OFF_IDX + (size_t)(r0 + t)] = (float)bj;
        out[OFF_OH + (size_t)(r0 + t) * 1024 + bj] = 1.0f;
        atomicAdd(&hist[bj], 1);
    }
    __syncthreads();

    // ---- z_q (straight-through) + loss partials -------------------------
    // Thread map t = c0*128 + r: channel class c0 = t>>7 (0..7), row r = t&127.
    // Wave q' = 2*c0 + g (g = r>>6) == R1's wave (class c0) over R1-block
    // 2*blockIdx+g: identical per-lane 8-term chains, identical shfl_down
    // butterfly, identical ascending-class sum -> partial[512] bit-identical.
    {
        const int r  = t & 127;
        const int c0 = t >> 7;
        const int row = r0 + r;
        const int bb2 = row >> 10;
        const int mm2 = row & 1023;
        const size_t zbr = (size_t)bb2 * 65536 + (size_t)mm2;
        const int    jjx = s_idx[r];
        const float* er  = emb + ((size_t)jjx << 6);
        float* zq = out + OFF_ZQ + zbr;
        float lsum = 0.f;
#pragma unroll
        for (int i = 0; i < 8; ++i) {
            int c = c0 + 8 * i;
            float zc   = z[zbr + (size_t)c * 1024];   // coalesced across r
            float ev   = er[c];                       // gather (L2-hot)
            float diff = ev - zc;
            zq[(size_t)c * 1024] = zc + diff;         // zp + (z_q - zp)
            lsum = fmaf(diff, diff, lsum);
        }
#pragma unroll
        for (int off = 32; off >= 1; off >>= 1) lsum += __shfl_down(lsum, off);
        if (lane == 0) s_l[q] = lsum;
        __syncthreads();
        if (t == 0) {
            float lA = 0.f, lB = 0.f;
#pragma unroll
            for (int c = 0; c < 8; ++c) {   // ascending class, as in R1
                lA += s_l[2 * c + 0];
                lB += s_l[2 * c + 1];
            }
            partial[2 * blockIdx.x + 0] = lA;
            partial[2 * blockIdx.x + 1] = lB;
        }
    }
}

__global__ __launch_bounds__(1024) void vq_final(const int* __restrict__ hist,
                                                 const float* __restrict__ partial,
                                                 float* __restrict__ out) {
    int t = threadIdx.x;
    float p    = (float)hist[t] * (1.0f / 32768.0f);
    float term = p * logf(p + 1e-10f);
    float lp   = (t < NPART) ? partial[t] : 0.f;
#pragma unroll
    for (int off = 32; off >= 1; off >>= 1) {
        term += __shfl_down(term, off);
        lp   += __shfl_down(lp, off);
    }
    __shared__ float st[16], sl[16];
    int w = t >> 6, ln = t & 63;
    if (ln == 0) { st[w] = term; sl[w] = lp; }
    __syncthreads();
    if (t == 0) {
        float s = 0.f, l = 0.f;
#pragma unroll
        for (int i = 0; i < 16; ++i) { s += st[i]; l += sl[i]; }
        out[OFF_LOSS] = 1.25f * l * (1.0f / 2097152.0f);  // (1+beta)*mean
        out[OFF_PERP] = expf(-s);
    }
}

extern "C" void kernel_launch(void* const* d_in, const int* in_sizes, int n_in,
                              void* d_out, int out_size, void* d_ws, size_t ws_size,
                              hipStream_t stream) {
    const float* z   = (const float*)d_in[0];
    const float* emb = (const float*)d_in[1];
    float* out     = (float*)d_out;
    int*   hist    = (int*)d_ws;
    float* partial = (float*)((char*)d_ws + 4096);

    hipMemsetAsync(hist, 0, 4096, stream);
    vq_main<<<NBLK, TPB, 0, stream>>>(z, emb, hist, partial, out);
    vq_final<<<1, 1024, 0, stream>>>(hist, partial, out);
}